// Round 9
// baseline (100.017 us; speedup 1.0000x reference)
//
#include <hip/hip_runtime.h>

// XCorrExt: B=32, S=160000, N=320, H=160, TAU=257, LAG_CUT=33
// out[b,f,tau-33] = 2*num/(e0 + e_tau + 1e-5), tau in [33,256]
// num[b,f,tau] = sum_n ext[tau+n]*frame[n]; frame[n] = xp[160f+n]
// ext[t] = xp[160f+t] (t<320) | xp[160f+t-160] (t>=320) | f=999,t>=320: x[t-320]
//
// R13 = R12 + 4-shift alignment replication for the B-operand stream.
// R12 analysis: dispatch ~40us, ~31us of it is the inner loop's B reads --
// 4x dword loads per step because the Hankel B pointer is only 4B-aligned
// (lane-dependent parity mod 4 dwords). Fix: FOUR half-shift copies
// cp_c[m] = s[m+c], c in [0,4); lane picks c = tb0 mod 4, making every
// B fragment start 8-half(16B)... >=8B aligned -> B = 2x ds_read_b64
// (single-address fast path) instead of 4x b32. T tail and s=8 bridge get
// the same 4-copy treatment. Copies built in P2 from one uint4-pair read
// per 8-dword chunk (+5 alignbits); copy stride 3152B (== 20 mod 32
// dwords) decorrelates copy bases across banks (<=2-way, free).
// LDS 24.7KB -> 6 blocks/CU (24 waves; DS-throughput-bound, enough).
// R12 recap: 16x16x544 Toeplitz GEMM/frame (mfma_f32_16x16x32_f16),
// A = frame read from s_h (b128-aligned), fold by pointer (pA/p8/pB),
// exact-fp32 energies via hierarchical block prefix sum.

typedef _Float16 f16;
typedef _Float16 h8 __attribute__((ext_vector_type(8)));
typedef _Float16 h4 __attribute__((ext_vector_type(4)));
typedef float    f4 __attribute__((ext_vector_type(4)));

#define S_LEN 160000
#define FN    1000
#define NF    8
#define BLOCK 256
#define USZ   1536              // staged signal floats: 160*(NF-1)+416

// smem byte offsets (all 16B-aligned)
#define ZPAD_OFF 0              // 16B zeros (A-frag OOB target)
#define SH_OFF   16             // cp0 = s_h: f16[1576] (zeros [1536,1576))
#define CPSTR    3152           // copy stride bytes (788 dw == 20 mod 32)
                                // cp_c at SH_OFF + CPSTR*c, c in [0,4)
#define TH_OFF   12624          // Tc0 = T_h: f16[288] (zeros [256,288))
#define TCSTR    576            // T copy stride bytes
#define BR_OFF   14928          // bridge: f16[4][8][32], BRc[c][fi][j]=ext_fi[304+j+c]
#define CSG_OFF  16976          // csg: float[1552] (excl. prefix of s^2)
#define CST_OFF  23184          // csT: float[260]
#define TOT_OFF  24224          // tot: float[260] (256 + wave sums)
#define SMEM_SZ  25264

__global__ __launch_bounds__(BLOCK)
void xcorr_kernel(const float* __restrict__ x, float* __restrict__ out) {
    __shared__ __align__(16) unsigned char smem[SMEM_SZ];
    f16*      zpad = (f16*)(smem + ZPAD_OFF);
    f16*      s_h  = (f16*)(smem + SH_OFF);
    f16*      T_h  = (f16*)(smem + TH_OFF);
    f16*      brA  = (f16*)(smem + BR_OFF);
    float*    csg  = (float*)(smem + CSG_OFF);
    float*    csT  = (float*)(smem + CST_OFF);
    float*    tot  = (float*)(smem + TOT_OFF);

    const int tid   = threadIdx.x;
    const int b     = blockIdx.y;
    const int fbase = blockIdx.x * NF;
    const long bOff = (long)b * S_LEN;
    const int gbase = fbase * 160;
    const bool lastBlk = (fbase + NF >= FN);

    // ---------------- P1: stage s_h (f16) + raw squares into csg --------------
    for (int i = 4*tid; i < USZ; i += 4*BLOCK) {
        const int gx = gbase + i;
        float v0, v1, v2, v3;
        if (gx + 3 < S_LEN) {
            const float4 v = *(const float4*)&x[bOff + gx];
            v0 = v.x; v1 = v.y; v2 = v.z; v3 = v.w;
        } else {
            v0 = (gx+0 < S_LEN) ? x[bOff+gx+0] : 0.f;
            v1 = (gx+1 < S_LEN) ? x[bOff+gx+1] : 0.f;
            v2 = (gx+2 < S_LEN) ? x[bOff+gx+2] : 0.f;
            v3 = (gx+3 < S_LEN) ? x[bOff+gx+3] : 0.f;
        }
        h4 hv; hv[0]=(f16)v0; hv[1]=(f16)v1; hv[2]=(f16)v2; hv[3]=(f16)v3;
        *(h4*)&s_h[i] = hv;
        f4 sq; sq[0]=v0*v0; sq[1]=v1*v1; sq[2]=v2*v2; sq[3]=v3*v3;
        *(f4*)&csg[i] = sq;
    }
    if (tid < 10) {                      // zero pad halves [1536,1576)
        h4 z; z[0]=(f16)0.f; z[1]=(f16)0.f; z[2]=(f16)0.f; z[3]=(f16)0.f;
        *(h4*)&s_h[1536 + 4*tid] = z;
    }
    if (tid < 16) csg[1536 + tid] = 0.f;
    if (tid == 0) { uint4 z; z.x=z.y=z.z=z.w=0u; *(uint4*)(smem + ZPAD_OFF) = z; }
    if (lastBlk) {
        for (int j = tid; j < 288; j += BLOCK) {
            const float tv = (j < 256) ? x[bOff + j] : 0.f;
            T_h[j] = (f16)tv;
            if (j < 260) csT[j] = tv * tv;
        }
    }
    __syncthreads();

    // ---------------- P2: build shifted copies + bridge; csg local prefix -----
    {
        // cp1/cp2/cp3: 776 dwords each (1552 halves), from one read pair.
        const unsigned* sd = (const unsigned*)s_h;
        for (int j = tid; j < 194; j += BLOCK) {
            const uint4 A  = *(const uint4*)(sd + 4*j);      // d0..d3
            const uint4 Bq = *(const uint4*)(sd + 4*j + 4);  // d4..d7
            uint4 c1, c2, c3;
            c1.x = __builtin_amdgcn_alignbit(A.y,  A.x, 16);
            c1.y = __builtin_amdgcn_alignbit(A.z,  A.y, 16);
            c1.z = __builtin_amdgcn_alignbit(A.w,  A.z, 16);
            c1.w = __builtin_amdgcn_alignbit(Bq.x, A.w, 16);
            c2.x = A.y; c2.y = A.z; c2.z = A.w; c2.w = Bq.x;
            c3.x = c1.y; c3.y = c1.z; c3.z = c1.w;
            c3.w = __builtin_amdgcn_alignbit(Bq.y, Bq.x, 16);
            *(uint4*)(smem + SH_OFF + 1*CPSTR + 16*j) = c1;
            *(uint4*)(smem + SH_OFF + 2*CPSTR + 16*j) = c2;
            *(uint4*)(smem + SH_OFF + 3*CPSTR + 16*j) = c3;
        }
        if (lastBlk) {                   // T copies: 136 dwords each
            const unsigned* Td = (const unsigned*)T_h;
            for (int j = tid; j < 34; j += BLOCK) {
                const uint4 A  = *(const uint4*)(Td + 4*j);
                const uint4 Bq = *(const uint4*)(Td + 4*j + 4);
                uint4 c1, c2, c3;
                c1.x = __builtin_amdgcn_alignbit(A.y,  A.x, 16);
                c1.y = __builtin_amdgcn_alignbit(A.z,  A.y, 16);
                c1.z = __builtin_amdgcn_alignbit(A.w,  A.z, 16);
                c1.w = __builtin_amdgcn_alignbit(Bq.x, A.w, 16);
                c2.x = A.y; c2.y = A.z; c2.z = A.w; c2.w = Bq.x;
                c3.x = c1.y; c3.y = c1.z; c3.z = c1.w;
                c3.w = __builtin_amdgcn_alignbit(Bq.y, Bq.x, 16);
                *(uint4*)(smem + TH_OFF + 1*TCSTR + 16*j) = c1;
                *(uint4*)(smem + TH_OFF + 2*TCSTR + 16*j) = c2;
                *(uint4*)(smem + TH_OFF + 3*TCSTR + 16*j) = c3;
            }
        }
        // bridge: BRc[c][fi][j] = ext_fi[304+j+c] (covers the s=8 straddle)
        {
            const int fi = tid >> 5, j = tid & 31;          // 256 threads
            const bool lastF = lastBlk && (fbase + fi == FN-1);
#pragma unroll
            for (int cc = 0; cc < 4; ++cc) {
                const int t = 304 + j + cc;
                f16 v;
                if (t < 320)      v = s_h[160*fi + t];
                else if (lastF)   v = T_h[t - 320];
                else              v = s_h[160*fi + t - 160];
                brA[256*cc + 32*fi + j] = v;
            }
        }
    }
    float p[7]; float mytot = 0.f;
    {
        const int t0 = 7*tid;
#pragma unroll
        for (int e = 0; e < 7; ++e) {
            const float r = (t0+e < 1552) ? csg[t0+e] : 0.f;
            p[e] = mytot;                       // exclusive within thread
            mytot += r;
        }
        tot[tid] = mytot;
    }
    __syncthreads();

    // ---------------- P3: all-wave scan (wave-local shfl + wave totals) -------
    const int lane = tid & 63;
    const int wv   = tid >> 6;
    {
        const float v = tot[tid];
        float sc = v;
#pragma unroll
        for (int d = 1; d < 64; d <<= 1) {
            const float o = __shfl_up(sc, d);
            sc += (lane >= d) ? o : 0.f;
        }
        tot[tid] = sc - v;                      // exclusive within wave
        if (lane == 63) tot[256 + wv] = sc;     // wave total
        if (lastBlk && wv == 0) {               // exclusive scan of csT (260)
            float r[5]; float mt = 0.f;
#pragma unroll
            for (int e = 0; e < 5; ++e) {
                const int j = 5*lane + e;
                const float rv = (j < 260) ? csT[j] : 0.f;
                r[e] = mt; mt += rv;
            }
            float sc2 = mt;
#pragma unroll
            for (int d = 1; d < 64; d <<= 1) {
                const float o = __shfl_up(sc2, d);
                sc2 += (lane >= d) ? o : 0.f;
            }
            const float b2 = sc2 - mt;
#pragma unroll
            for (int e = 0; e < 5; ++e) {
                const int j = 5*lane + e;
                if (j < 260) csT[j] = b2 + r[e];
            }
        }
    }
    __syncthreads();

    // ---------------- P4: apply csg bases (exclusive prefix complete) ---------
    {
        const float w1 = tot[256], w2 = tot[257], w3 = tot[258];
        const float wbase = ((wv > 0) ? w1 : 0.f) + ((wv > 1) ? w2 : 0.f)
                          + ((wv > 2) ? w3 : 0.f);
        const float base = wbase + tot[tid];
        const int t0 = 7*tid;
#pragma unroll
        for (int e = 0; e < 7; ++e)
            if (t0+e < 1552) csg[t0+e] = base + p[e];
    }
    __syncthreads();

    // ---------------- compute: wave wv -> frames 2wv, 2wv+1 -------------------
    const int col  = lane & 15;          // A-row t1-lane, B-col t0, C-col
    const int q    = lane >> 4;          // k-group; C-row = 4q+v
    const int off0 = 8*q - 16*col;       // A: off = j - 16*row, j = 32s+8q
    const int tb0  = 33 + col + 8*q;     // B: half index base into ext, [33,72]
    const int c    = tb0 & 3;            // shift copy select; tb0-c == 0 mod 4
    const unsigned* cpd = (const unsigned*)(smem + SH_OFF + CPSTR*c);
    const unsigned* Tcd = (const unsigned*)(smem + TH_OFF + TCSTR*c);
    const unsigned* brd = (const unsigned*)(brA + 256*c);

#pragma unroll 1
    for (int ff = 0; ff < 2; ++ff) {
        const int fi = 2*wv + ff;
        const int f  = fbase + fi;
        const bool isLast = (f == FN-1);
        const f16* frame = s_h + 160*fi;
        const int dA0 = (160*fi + tb0 - c) >> 1;             // even dword idx
        const unsigned* pA = cpd + dA0;                      // group all t<320
        const unsigned* pB = isLast ? (Tcd + ((tb0 - 320 - c) >> 1))
                                    : (pA - 80);             // group all t>=320
        // s=8: start t = tb0+256: <=312 -> pA; 313..319 -> bridge; >=320 -> pB
        const unsigned* p8 = (tb0 <= 56) ? pA
                           : ((tb0 <= 63) ? (brd + 16*fi + ((tb0 - 48 - c) >> 1) - 128)
                                          : pB);
        f4 acc = {0.f, 0.f, 0.f, 0.f};
#pragma unroll
        for (int s = 0; s < 17; ++s) {
            const int off = off0 + 32*s;
            const f16* ap = ((unsigned)off <= 312u) ? (frame + off) : zpad;
            const h8 a = *(const h8*)ap;                     // aligned b128
            const unsigned* bp = (s < 8) ? pA : ((s == 8) ? p8 : pB);
            const uint2 b0 = *(const uint2*)(bp + 16*s);     // aligned b64
            const uint2 b1 = *(const uint2*)(bp + 16*s + 2); // aligned b64
            union { unsigned u[4]; h8 h; } Bf;
            Bf.u[0] = b0.x; Bf.u[1] = b0.y; Bf.u[2] = b1.x; Bf.u[3] = b1.y;
            acc = __builtin_amdgcn_mfma_f32_16x16x32_f16(a, Bf.h, acc, 0, 0, 0);
        }
        // epilogue: energies from exact-fp32 prefix sums
        const int D = 160*fi;
        const float c0   = csg[D];
        const float c160 = csg[D+160];
        const float c320 = csg[D+320];
        const float e0   = c320 - c0;
        float* op = &out[(long)(b*FN + f) * 224];
#pragma unroll
        for (int v = 0; v < 4; ++v) {
            const int t1 = 4*q + v;
            if (t1 <= 13) {
                const int tau = 33 + 16*t1 + col;
                const float et = isLast
                    ? (c320 - csg[D+tau] + csT[tau])
                    : (c320 - csg[D+tau] - c160 + csg[D+160+tau]);
                const float den = e0 + et + 1e-5f;
                op[tau - 33] = 2.f * acc[v] * __builtin_amdgcn_rcpf(den);
            }
        }
    }
}

extern "C" void kernel_launch(void* const* d_in, const int* in_sizes, int n_in,
                              void* d_out, int out_size, void* d_ws, size_t ws_size,
                              hipStream_t stream) {
    const float* x = (const float*)d_in[0];
    float* out = (float*)d_out;
    dim3 grid(FN / NF, 32);              // (125, 32) = 4000 blocks
    dim3 block(BLOCK);
    hipLaunchKernelGGL(xcorr_kernel, grid, block, 0, stream, x, out);
}